// Round 1
// baseline (642.157 us; speedup 1.0000x reference)
//
#include <hip/hip_runtime.h>
#include <stdint.h>

#define NB 4
#define NC 17
#define BB 8
#define HH 8
#define SS 512
#define DD 64

// ws layout (bytes):
//   W1m  : [17][8][64][64] f32   = 2,228,224 B
//   T    : [8][8][512][5][64] bf16 = 20,971,520 B
//   ridx : [8][512] int          = 16,384 B   (row indices grouped by bi)
//   gst  : [8][6] int            = 192 B      (group start offsets per b)
#define WS_W1   0
#define WS_T    2228224
#define WS_RIDX (WS_T + 20971520)
#define WS_GST  (WS_RIDX + 16384)

__device__ __forceinline__ float bf2f(unsigned int hi16) {
  // hi16 already shifted: pass (u & 0xffff0000) or (u << 16)
  float f; __builtin_memcpy(&f, &hi16, 4); return f;
}
__device__ __forceinline__ unsigned short f2bf(float f) {
  unsigned int x; __builtin_memcpy(&x, &f, 4);
  unsigned int r = (x + 0x7fff + ((x >> 16) & 1)) >> 16;
  return (unsigned short)r;
}

// ---- K0: per-b counting sort of rows by bucket bi ----
__global__ void k_group(const int* __restrict__ bseq, int* __restrict__ ridx,
                        int* __restrict__ gst) {
  int b = blockIdx.x, tid = threadIdx.x;
  __shared__ int cnt[5], base[6], cur[5];
  if (tid < 5) cnt[tid] = 0;
  __syncthreads();
  for (int j = tid; j < SS; j += blockDim.x) atomicAdd(&cnt[bseq[b * SS + j]], 1);
  __syncthreads();
  if (tid == 0) {
    base[0] = 0;
    for (int k = 0; k < 5; k++) base[k + 1] = base[k] + cnt[k];
    for (int k = 0; k < 6; k++) gst[b * 6 + k] = base[k];
  }
  __syncthreads();
  if (tid < 5) cur[tid] = base[tid];
  __syncthreads();
  for (int j = tid; j < SS; j += blockDim.x) {
    int p = atomicAdd(&cur[bseq[b * SS + j]], 1);
    ridx[b * SS + p] = j;
  }
}

// ---- K1: W1m[c][h][m][n] = sum_B W1[B][h][m][n] * softmax(alpha1, axis=B)[c,B,h] ----
__global__ void k_w1(const float* __restrict__ W1, const float* __restrict__ alpha,
                     float* __restrict__ W1m) {
  int c = blockIdx.x >> 3, hh = blockIdx.x & 7, tid = threadIdx.x;
  __shared__ float sm[NB];
  if (tid == 0) {
    float a[NB], mx = -1e30f;
    for (int B = 0; B < NB; B++) { a[B] = alpha[(c * NB + B) * HH + hh]; mx = fmaxf(mx, a[B]); }
    float s = 0.f, e[NB];
    for (int B = 0; B < NB; B++) { e[B] = __expf(a[B] - mx); s += e[B]; }
    for (int B = 0; B < NB; B++) sm[B] = e[B] / s;
  }
  __syncthreads();
  for (int idx = tid; idx < DD * DD; idx += blockDim.x) {
    int m = idx >> 6, n = idx & 63;
    float v = 0.f;
    for (int B = 0; B < NB; B++) v += W1[((B * HH + hh) * DD + m) * DD + n] * sm[B];
    W1m[((c * HH + hh) * DD + m) * DD + n] = v;
  }
}

// ---- K2: T[bh][j][B][m] = sum_n W1m[c(B,bj)][h][m][n] * key[bh][j][n]  (bf16 out) ----
__global__ __launch_bounds__(256) void k_T(const float* __restrict__ key,
                                           const int* __restrict__ bseq,
                                           const float* __restrict__ W1m,
                                           unsigned short* __restrict__ T) {
  int bx = blockIdx.x;
  int jt = bx & 7, bh = bx >> 3, b = bh >> 3, h = bh & 7;
  int j0 = jt * 64, tid = threadIdx.x;
  __shared__ float klds[64][68];
  __shared__ int bjl[64], ord[64];
  for (int idx = tid; idx < 64 * 16; idx += 256) {
    int jj = idx >> 4, nq = idx & 15;
    float4 v = *(const float4*)&key[((size_t)(bh * SS + j0 + jj)) * DD + nq * 4];
    *(float4*)&klds[jj][nq * 4] = v;
  }
  if (tid < 64) bjl[tid] = bseq[b * SS + j0 + tid];
  __syncthreads();
  if (tid == 0) {  // order columns by bucket so same W-class runs stay L1-resident
    int cnt[5] = {0, 0, 0, 0, 0};
    for (int j = 0; j < 64; j++) cnt[bjl[j]]++;
    int off[5]; off[0] = 0;
    for (int k = 1; k < 5; k++) off[k] = off[k - 1] + cnt[k - 1];
    for (int j = 0; j < 64; j++) ord[off[bjl[j]]++] = j;
  }
  __syncthreads();
  int m = tid & 63, g = tid >> 6;
  for (int p = g; p < 5 * 64; p += 4) {
    int B = p >> 6, oj = p & 63;
    int jj = ord[oj], bj = bjl[jj];
    int c = (B == 0 || bj == 0) ? 0 : (B - 1) * NB + bj;
    const float4* wrow = (const float4*)&W1m[(((size_t)(c * HH + h)) * DD + m) * DD];
    float acc = 0.f;
#pragma unroll
    for (int nq = 0; nq < 16; nq++) {
      float4 w = wrow[nq];
      float4 kk = *(const float4*)&klds[jj][nq * 4];
      acc += w.x * kk.x + w.y * kk.y + w.z * kk.z + w.w * kk.w;
    }
    T[(((size_t)(bh * SS + j0 + jj)) * 5 + B) * DD + m] = f2bf(acc);
  }
}

// ---- K3: scores[bh][i][j] = dot(q[i,:], T[j][bi,:]) over grouped rows ----
__global__ __launch_bounds__(256) void k_scores(const float* __restrict__ query,
                                                const unsigned short* __restrict__ T,
                                                const int* __restrict__ ridx,
                                                const int* __restrict__ gst,
                                                float* __restrict__ out) {
  int bx = blockIdx.x;
  int st = bx & 15, tmp = bx >> 4;
  int B = tmp % 5, bh = tmp / 5, b = bh >> 3;
  int tid = threadIdx.x;
  int gs = gst[b * 6 + B], ge = gst[b * 6 + B + 1];
  int row0 = gs + st * 32;
  if (row0 >= ge) return;
  int nrows = ge - row0; if (nrows > 32) nrows = 32;
  __shared__ float qlds[32][68];
  __shared__ float Tl[64][68];
  __shared__ int irow[32];
  if (tid < 32) irow[tid] = (tid < nrows) ? ridx[b * SS + row0 + tid] : 0;
  __syncthreads();
  for (int idx = tid; idx < 32 * 16; idx += 256) {
    int r = idx >> 4, mq = idx & 15;
    float4 v = make_float4(0.f, 0.f, 0.f, 0.f);
    if (r < nrows) v = *(const float4*)&query[((size_t)(bh * SS + irow[r])) * DD + mq * 4];
    *(float4*)&qlds[r][mq * 4] = v;
  }
  int rg = tid >> 6, jl = tid & 63;
  for (int jt = 0; jt < 8; jt++) {
    int j0 = jt * 64;
    __syncthreads();
    for (int idx = tid; idx < 64 * 8; idx += 256) {
      int jj = idx >> 3, mo = idx & 7;
      uint4 raw = *(const uint4*)&T[(((size_t)(bh * SS + j0 + jj)) * 5 + B) * DD + mo * 8];
      float* dst = &Tl[jj][mo * 8];
      dst[0] = bf2f(raw.x << 16); dst[1] = bf2f(raw.x & 0xffff0000u);
      dst[2] = bf2f(raw.y << 16); dst[3] = bf2f(raw.y & 0xffff0000u);
      dst[4] = bf2f(raw.z << 16); dst[5] = bf2f(raw.z & 0xffff0000u);
      dst[6] = bf2f(raw.w << 16); dst[7] = bf2f(raw.w & 0xffff0000u);
    }
    __syncthreads();
    float acc[8];
#pragma unroll
    for (int rr = 0; rr < 8; rr++) acc[rr] = 0.f;
#pragma unroll 4
    for (int mq = 0; mq < 16; mq++) {
      float4 t4 = *(const float4*)&Tl[jl][mq * 4];
#pragma unroll
      for (int rr = 0; rr < 8; rr++) {
        float4 q4 = *(const float4*)&qlds[rg * 8 + rr][mq * 4];
        acc[rr] += q4.x * t4.x + q4.y * t4.y + q4.z * t4.z + q4.w * t4.w;
      }
    }
#pragma unroll
    for (int rr = 0; rr < 8; rr++) {
      int r = rg * 8 + rr;
      if (r < nrows) out[((size_t)(bh * SS + irow[r])) * SS + j0 + jl] = acc[rr];
    }
  }
}

extern "C" void kernel_launch(void* const* d_in, const int* in_sizes, int n_in,
                              void* d_out, int out_size, void* d_ws, size_t ws_size,
                              hipStream_t stream) {
  const float* q = (const float*)d_in[0];
  const float* k = (const float*)d_in[1];
  const int* bseq = (const int*)d_in[2];
  const float* W1 = (const float*)d_in[3];
  const float* alpha = (const float*)d_in[4];
  float* out = (float*)d_out;
  char* ws = (char*)d_ws;
  float* W1m = (float*)(ws + WS_W1);
  unsigned short* T = (unsigned short*)(ws + WS_T);
  int* ridx = (int*)(ws + WS_RIDX);
  int* gst = (int*)(ws + WS_GST);

  hipLaunchKernelGGL(k_group, dim3(8), dim3(256), 0, stream, bseq, ridx, gst);
  hipLaunchKernelGGL(k_w1, dim3(NC * HH), dim3(256), 0, stream, W1, alpha, W1m);
  hipLaunchKernelGGL(k_T, dim3(8 * BB * HH), dim3(256), 0, stream, k, bseq, W1m, T);
  hipLaunchKernelGGL(k_scores, dim3(16 * 5 * BB * HH), dim3(256), 0, stream, q, T, ridx, gst, out);
}

// Round 2
// 139.484 us; speedup vs baseline: 4.6038x; 4.6038x over previous
//
#include <hip/hip_runtime.h>
#include <stdint.h>

#define NB 4
#define NC 17
#define HH 8
#define SS 512
#define DD 64

typedef __attribute__((ext_vector_type(8))) short bf16x8;
typedef __attribute__((ext_vector_type(4))) float f32x4;

// ws layout (bytes):
//   W1mbf : [17][8][64][64] bf16 = 1,114,112
//   Tg    : [64 bh][5 B][512 j][64 m] bf16 = 20,971,520
//   ridx  : [8][512] int (rows/cols grouped by bucket)
//   gst   : [8][6] int group offsets
#define WS_W1   0
#define WS_T    1114112
#define WS_RIDX (WS_T + 20971520)
#define WS_GST  (WS_RIDX + 16384)

__device__ __forceinline__ unsigned short f2bf(float f) {
  unsigned int x; __builtin_memcpy(&x, &f, 4);
  return (unsigned short)((x + 0x7fff + ((x >> 16) & 1)) >> 16);
}
// load 8 consecutive floats, round to bf16, pack into MFMA A/B fragment
__device__ __forceinline__ bf16x8 cvt8(const float* p) {
  float4 a = *(const float4*)p;
  float4 b = *(const float4*)(p + 4);
  union { bf16x8 v; unsigned short u[8]; } t;
  t.u[0] = f2bf(a.x); t.u[1] = f2bf(a.y); t.u[2] = f2bf(a.z); t.u[3] = f2bf(a.w);
  t.u[4] = f2bf(b.x); t.u[5] = f2bf(b.y); t.u[6] = f2bf(b.z); t.u[7] = f2bf(b.w);
  return t.v;
}

// ---- K0: blocks 0..7: per-b counting sort of positions by bucket.
//          blocks 8..143: W1mbf[c][h][m][n] = sum_B W1[B][h][m][n]*softmax(alpha)[c,B,h]
__global__ __launch_bounds__(256) void k_prep(const int* __restrict__ bseq,
                                              const float* __restrict__ W1,
                                              const float* __restrict__ alpha,
                                              int* __restrict__ ridx,
                                              int* __restrict__ gst,
                                              unsigned short* __restrict__ W1mbf) {
  int tid = threadIdx.x;
  if (blockIdx.x < 8) {
    int b = blockIdx.x;
    __shared__ int cnt[5], base[6], cur[5];
    if (tid < 5) cnt[tid] = 0;
    __syncthreads();
    for (int j = tid; j < SS; j += blockDim.x) atomicAdd(&cnt[bseq[b * SS + j]], 1);
    __syncthreads();
    if (tid == 0) {
      base[0] = 0;
      for (int k = 0; k < 5; k++) base[k + 1] = base[k] + cnt[k];
      for (int k = 0; k < 6; k++) gst[b * 6 + k] = base[k];
    }
    __syncthreads();
    if (tid < 5) cur[tid] = base[tid];
    __syncthreads();
    for (int j = tid; j < SS; j += blockDim.x) {
      int p = atomicAdd(&cur[bseq[b * SS + j]], 1);
      ridx[b * SS + p] = j;
    }
  } else {
    int cb = blockIdx.x - 8;
    int c = cb >> 3, hh = cb & 7;
    __shared__ float sm[NB];
    if (tid == 0) {
      float a[NB], mx = -1e30f;
      for (int B = 0; B < NB; B++) { a[B] = alpha[(c * NB + B) * HH + hh]; mx = fmaxf(mx, a[B]); }
      float s = 0.f;
      for (int B = 0; B < NB; B++) { a[B] = __expf(a[B] - mx); s += a[B]; }
      for (int B = 0; B < NB; B++) sm[B] = a[B] / s;
    }
    __syncthreads();
    float s0 = sm[0], s1 = sm[1], s2 = sm[2], s3 = sm[3];
    for (int idx = tid; idx < DD * DD; idx += blockDim.x) {
      float v = W1[((0 * HH + hh) * DD * DD) + idx] * s0 +
                W1[((1 * HH + hh) * DD * DD) + idx] * s1 +
                W1[((2 * HH + hh) * DD * DD) + idx] * s2 +
                W1[((3 * HH + hh) * DD * DD) + idx] * s3;
      W1mbf[((size_t)(c * HH + hh)) * DD * DD + idx] = f2bf(v);
    }
  }
}

// ---- K1: Tg[bh][B][j][m] = sum_n key[bh][j][n] * W_{c(B,bj_j)}[m][n]  via MFMA ----
// columns processed in bj-grouped order so each 16-row M-tile has a uniform class.
__global__ __launch_bounds__(256) void k_T(const float* __restrict__ key,
                                           const unsigned short* __restrict__ W1mbf,
                                           const int* __restrict__ ridx,
                                           const int* __restrict__ gst,
                                           unsigned short* __restrict__ Tg) {
  int bx = blockIdx.x;
  int half = bx & 1, t = bx >> 1;
  int B = t % 5, bh = t / 5, b = bh >> 3, h = bh & 7;
  int tid = threadIdx.x, wave = tid >> 6, lane = tid & 63;
  int quad = lane >> 4, l16 = lane & 15;
  int slot = wave + 4 * half;
  int flat = 0;
  for (int a = 0; a < 5; a++) {
    int gs = gst[b * 6 + a], ge = gst[b * 6 + a + 1];
    int c = (B == 0 || a == 0) ? 0 : (B - 1) * NB + a;
    const unsigned short* Wc = W1mbf + (size_t)(c * HH + h) * DD * DD;
    for (int p0 = gs; p0 < ge; p0 += 16, flat++) {
      if ((flat & 7) != slot) continue;
      int p = p0 + l16; if (p > ge - 1) p = ge - 1;
      int j = ridx[b * SS + p];
      const float* kp = &key[((size_t)(bh * SS + j)) * DD + quad * 8];
      bf16x8 af0 = cvt8(kp);        // k = 0..31  (quad*8 + jj)
      bf16x8 af1 = cvt8(kp + 32);   // k = 32..63
      f32x4 accs[4];
#pragma unroll
      for (int nt = 0; nt < 4; nt++) {
        const unsigned short* wp = &Wc[(nt * 16 + l16) * DD + quad * 8];
        bf16x8 b0 = *(const bf16x8*)wp;
        bf16x8 b1 = *(const bf16x8*)(wp + 32);
        f32x4 acc = {0.f, 0.f, 0.f, 0.f};
        acc = __builtin_amdgcn_mfma_f32_16x16x32_bf16(af0, b0, acc, 0, 0, 0);
        acc = __builtin_amdgcn_mfma_f32_16x16x32_bf16(af1, b1, acc, 0, 0, 0);
        accs[nt] = acc;
      }
      int jr[4];
#pragma unroll
      for (int reg = 0; reg < 4; reg++) {
        int pr = p0 + quad * 4 + reg;
        jr[reg] = (pr < ge) ? ridx[b * SS + pr] : -1;
      }
#pragma unroll
      for (int nt = 0; nt < 4; nt++)
#pragma unroll
        for (int reg = 0; reg < 4; reg++)
          if (jr[reg] >= 0)
            Tg[((size_t)((bh * 5 + B) * SS + jr[reg])) * DD + nt * 16 + l16] =
                f2bf(accs[nt][reg]);
    }
  }
}

// ---- K2: out[bh][i][j] = sum_m q[bh][i][m] * Tg[bh][bi_i][j][m]  via MFMA ----
__global__ __launch_bounds__(256) void k_scores(const float* __restrict__ query,
                                                const unsigned short* __restrict__ Tg,
                                                const int* __restrict__ ridx,
                                                const int* __restrict__ gst,
                                                float* __restrict__ out) {
  int bx = blockIdx.x;
  int jq = bx & 3, t = bx >> 2;           // jq: which 128-column quarter
  int B = t % 5, bh = t / 5, b = bh >> 3;
  int tid = threadIdx.x, wave = tid >> 6, lane = tid & 63;
  int quad = lane >> 4, l16 = lane & 15;
  int gs = gst[b * 6 + B], ge = gst[b * 6 + B + 1];
  int n = ge - gs;
  if (n <= 0) return;
  const unsigned short* Tp = Tg + (size_t)(bh * 5 + B) * SS * DD;
  for (int mt = wave; mt * 16 < n; mt += 4) {
    int p0 = gs + mt * 16;
    int p = p0 + l16; if (p > ge - 1) p = ge - 1;
    int r = ridx[b * SS + p];
    const float* qp = &query[((size_t)(bh * SS + r)) * DD + quad * 8];
    bf16x8 af0 = cvt8(qp);
    bf16x8 af1 = cvt8(qp + 32);
    int rr[4];
#pragma unroll
    for (int reg = 0; reg < 4; reg++) {
      int pr = p0 + quad * 4 + reg;
      rr[reg] = (pr < ge) ? ridx[b * SS + pr] : -1;
    }
#pragma unroll
    for (int nt8 = 0; nt8 < 8; nt8++) {
      int j0 = (jq * 8 + nt8) * 16;
      const unsigned short* tp = &Tp[(size_t)(j0 + l16) * DD + quad * 8];
      bf16x8 b0 = *(const bf16x8*)tp;
      bf16x8 b1 = *(const bf16x8*)(tp + 32);
      f32x4 acc = {0.f, 0.f, 0.f, 0.f};
      acc = __builtin_amdgcn_mfma_f32_16x16x32_bf16(af0, b0, acc, 0, 0, 0);
      acc = __builtin_amdgcn_mfma_f32_16x16x32_bf16(af1, b1, acc, 0, 0, 0);
#pragma unroll
      for (int reg = 0; reg < 4; reg++)
        if (rr[reg] >= 0)
          out[((size_t)(bh * SS + rr[reg])) * SS + j0 + l16] = acc[reg];
    }
  }
}

extern "C" void kernel_launch(void* const* d_in, const int* in_sizes, int n_in,
                              void* d_out, int out_size, void* d_ws, size_t ws_size,
                              hipStream_t stream) {
  const float* q = (const float*)d_in[0];
  const float* k = (const float*)d_in[1];
  const int* bseq = (const int*)d_in[2];
  const float* W1 = (const float*)d_in[3];
  const float* alpha = (const float*)d_in[4];
  float* out = (float*)d_out;
  char* ws = (char*)d_ws;
  unsigned short* W1mbf = (unsigned short*)(ws + WS_W1);
  unsigned short* Tg = (unsigned short*)(ws + WS_T);
  int* ridx = (int*)(ws + WS_RIDX);
  int* gst = (int*)(ws + WS_GST);

  hipLaunchKernelGGL(k_prep, dim3(8 + NC * HH), dim3(256), 0, stream,
                     bseq, W1, alpha, ridx, gst, W1mbf);
  hipLaunchKernelGGL(k_T, dim3(64 * 5 * 2), dim3(256), 0, stream,
                     k, W1mbf, ridx, gst, Tg);
  hipLaunchKernelGGL(k_scores, dim3(64 * 5 * 4), dim3(256), 0, stream,
                     q, Tg, ridx, gst, out);
}

// Round 3
// 124.212 us; speedup vs baseline: 5.1699x; 1.1230x over previous
//
#include <hip/hip_runtime.h>
#include <stdint.h>

#define NB 4
#define NC 17
#define HH 8
#define SS 512
#define DD 64

typedef __attribute__((ext_vector_type(8))) short bf16x8;
typedef __attribute__((ext_vector_type(4))) float f32x4;

// ws layout (bytes):
//   W1mbf : [17][8][64][64] bf16 = 1,114,112
//   ridx  : [8][512] int (rows grouped by bucket)
//   gst   : [8][6] int group offsets
#define WS_W1   0
#define WS_RIDX 1114112
#define WS_GST  (WS_RIDX + 16384)

__device__ __forceinline__ unsigned short f2bf(float f) {
  unsigned int x; __builtin_memcpy(&x, &f, 4);
  return (unsigned short)((x + 0x7fff + ((x >> 16) & 1)) >> 16);
}
// load 8 consecutive floats, round to bf16, pack into MFMA A/B fragment
__device__ __forceinline__ bf16x8 cvt8(const float* p) {
  float4 a = *(const float4*)p;
  float4 b = *(const float4*)(p + 4);
  union { bf16x8 v; unsigned short u[8]; } t;
  t.u[0] = f2bf(a.x); t.u[1] = f2bf(a.y); t.u[2] = f2bf(a.z); t.u[3] = f2bf(a.w);
  t.u[4] = f2bf(b.x); t.u[5] = f2bf(b.y); t.u[6] = f2bf(b.z); t.u[7] = f2bf(b.w);
  return t.v;
}

// ---- K0: blocks 0..7: per-b counting sort of row positions by bucket bi.
//          blocks 8..143: W1mbf[c][h][.] = sum_B W1[B][h][.]*softmax(alpha)[c,B,h]
__global__ __launch_bounds__(256) void k_prep(const int* __restrict__ bseq,
                                              const float* __restrict__ W1,
                                              const float* __restrict__ alpha,
                                              int* __restrict__ ridx,
                                              int* __restrict__ gst,
                                              unsigned short* __restrict__ W1mbf) {
  int tid = threadIdx.x;
  if (blockIdx.x < 8) {
    int b = blockIdx.x;
    __shared__ int cnt[5], base[6], cur[5];
    if (tid < 5) cnt[tid] = 0;
    __syncthreads();
    for (int j = tid; j < SS; j += blockDim.x) atomicAdd(&cnt[bseq[b * SS + j]], 1);
    __syncthreads();
    if (tid == 0) {
      base[0] = 0;
      for (int k = 0; k < 5; k++) base[k + 1] = base[k] + cnt[k];
      for (int k = 0; k < 6; k++) gst[b * 6 + k] = base[k];
    }
    __syncthreads();
    if (tid < 5) cur[tid] = base[tid];
    __syncthreads();
    for (int j = tid; j < SS; j += blockDim.x) {
      int p = atomicAdd(&cur[bseq[b * SS + j]], 1);
      ridx[b * SS + p] = j;
    }
  } else {
    int cb = blockIdx.x - 8;
    int c = cb >> 3, hh = cb & 7;
    __shared__ float sm[NB];
    if (tid == 0) {
      float a[NB], mx = -1e30f;
      for (int B = 0; B < NB; B++) { a[B] = alpha[(c * NB + B) * HH + hh]; mx = fmaxf(mx, a[B]); }
      float s = 0.f;
      for (int B = 0; B < NB; B++) { a[B] = __expf(a[B] - mx); s += a[B]; }
      for (int B = 0; B < NB; B++) sm[B] = a[B] / s;
    }
    __syncthreads();
    float s0 = sm[0], s1 = sm[1], s2 = sm[2], s3 = sm[3];
    for (int idx = tid; idx < DD * DD; idx += blockDim.x) {
      float v = W1[((0 * HH + hh) * DD * DD) + idx] * s0 +
                W1[((1 * HH + hh) * DD * DD) + idx] * s1 +
                W1[((2 * HH + hh) * DD * DD) + idx] * s2 +
                W1[((3 * HH + hh) * DD * DD) + idx] * s3;
      W1mbf[((size_t)(c * HH + hh)) * DD * DD + idx] = f2bf(v);
    }
  }
}

// ---- Fused: per (bh, 128-col tile): build T[5][128][64] in LDS, then scores GEMM.
__global__ __launch_bounds__(512) void k_fused(const float* __restrict__ query,
                                               const float* __restrict__ key,
                                               const int* __restrict__ bseq,
                                               const unsigned short* __restrict__ W1mbf,
                                               const int* __restrict__ ridx,
                                               const int* __restrict__ gst,
                                               float* __restrict__ out) {
  int bx = blockIdx.x;
  int jt = bx & 3, bh = bx >> 2, b = bh >> 3, h = bh & 7;
  int j0 = jt * 128;
  int tid = threadIdx.x, wave = tid >> 6, lane = tid & 63;
  int quad = lane >> 4, l16 = lane & 15;

  // T LDS: [plane B][local col][feature padded to 72] — col stride 144 B
  __shared__ __align__(16) unsigned short Tl[5][128][72];
  __shared__ int ord[128], lgs[6], cnt[5], cur[5];

  // ---- local column grouping by bj ----
  if (tid < 5) cnt[tid] = 0;
  __syncthreads();
  int mybj = 0;
  if (tid < 128) { mybj = bseq[b * SS + j0 + tid]; atomicAdd(&cnt[mybj], 1); }
  __syncthreads();
  if (tid == 0) {
    lgs[0] = 0;
    for (int a = 0; a < 5; a++) lgs[a + 1] = lgs[a] + cnt[a];
  }
  __syncthreads();
  if (tid < 5) cur[tid] = lgs[tid];
  __syncthreads();
  if (tid < 128) ord[atomicAdd(&cur[mybj], 1)] = tid;
  __syncthreads();

  // ---- phase 1: T[B][col][m] = sum_n key[col][n] * W_c(B,bj)[m][n] ----
  int flat = 0;
  for (int a = 0; a < 5; a++) {
    int ls = lgs[a], le = lgs[a + 1];
    if (le <= ls) continue;
    int nB = (a == 0) ? 1 : 5;  // bj=0 columns: class 0 for every plane
    for (int B = 0; B < nB; B++) {
      int c = (B == 0) ? 0 : (B - 1) * NB + a;
      const unsigned short* Wc = W1mbf + (size_t)(c * HH + h) * DD * DD;
      for (int t0 = ls; t0 < le; t0 += 16, flat++) {
        if ((flat & 7) != wave) continue;
        int p = t0 + l16; if (p > le - 1) p = le - 1;
        int cl = ord[p];
        const float* kp = &key[((size_t)(bh * SS + j0 + cl)) * DD + quad * 8];
        bf16x8 af0 = cvt8(kp);
        bf16x8 af1 = cvt8(kp + 32);
        int cr[4];
#pragma unroll
        for (int reg = 0; reg < 4; reg++) {
          int pr = t0 + quad * 4 + reg;
          cr[reg] = (pr < le) ? ord[pr] : -1;
        }
#pragma unroll
        for (int nt = 0; nt < 4; nt++) {
          const unsigned short* wp = &Wc[(nt * 16 + l16) * DD + quad * 8];
          bf16x8 b0 = *(const bf16x8*)wp;
          bf16x8 b1 = *(const bf16x8*)(wp + 32);
          f32x4 acc = {0.f, 0.f, 0.f, 0.f};
          acc = __builtin_amdgcn_mfma_f32_16x16x32_bf16(af0, b0, acc, 0, 0, 0);
          acc = __builtin_amdgcn_mfma_f32_16x16x32_bf16(af1, b1, acc, 0, 0, 0);
#pragma unroll
          for (int reg = 0; reg < 4; reg++) {
            if (cr[reg] >= 0) {
              unsigned short v = f2bf(acc[reg]);
              if (a == 0) {
#pragma unroll
                for (int Bw = 0; Bw < 5; Bw++) Tl[Bw][cr[reg]][nt * 16 + l16] = v;
              } else {
                Tl[B][cr[reg]][nt * 16 + l16] = v;
              }
            }
          }
        }
      }
    }
  }
  __syncthreads();

  // ---- phase 2: out[i][j0+jj] = q[i,:].T dot Tl[B(i)][jj][:] ----
  flat = 0;
  for (int B = 0; B < 5; B++) {
    int gs = gst[b * 6 + B], ge = gst[b * 6 + B + 1];
    if (ge <= gs) continue;
    for (int p0 = gs; p0 < ge; p0 += 16, flat++) {
      if ((flat & 7) != wave) continue;
      int p = p0 + l16; if (p > ge - 1) p = ge - 1;
      int r = ridx[b * SS + p];
      const float* qp = &query[((size_t)(bh * SS + r)) * DD + quad * 8];
      bf16x8 af0 = cvt8(qp);
      bf16x8 af1 = cvt8(qp + 32);
      int rr[4];
#pragma unroll
      for (int reg = 0; reg < 4; reg++) {
        int pr = p0 + quad * 4 + reg;
        rr[reg] = (pr < ge) ? ridx[b * SS + pr] : -1;
      }
#pragma unroll
      for (int ct = 0; ct < 8; ct++) {
        const unsigned short* tp = &Tl[B][ct * 16 + l16][quad * 8];
        bf16x8 b0 = *(const bf16x8*)tp;
        bf16x8 b1 = *(const bf16x8*)(tp + 32);
        f32x4 acc = {0.f, 0.f, 0.f, 0.f};
        acc = __builtin_amdgcn_mfma_f32_16x16x32_bf16(af0, b0, acc, 0, 0, 0);
        acc = __builtin_amdgcn_mfma_f32_16x16x32_bf16(af1, b1, acc, 0, 0, 0);
#pragma unroll
        for (int reg = 0; reg < 4; reg++)
          if (rr[reg] >= 0)
            out[((size_t)(bh * SS + rr[reg])) * SS + j0 + ct * 16 + l16] = acc[reg];
      }
    }
  }
}

extern "C" void kernel_launch(void* const* d_in, const int* in_sizes, int n_in,
                              void* d_out, int out_size, void* d_ws, size_t ws_size,
                              hipStream_t stream) {
  const float* q = (const float*)d_in[0];
  const float* k = (const float*)d_in[1];
  const int* bseq = (const int*)d_in[2];
  const float* W1 = (const float*)d_in[3];
  const float* alpha = (const float*)d_in[4];
  float* out = (float*)d_out;
  char* ws = (char*)d_ws;
  unsigned short* W1mbf = (unsigned short*)(ws + WS_W1);
  int* ridx = (int*)(ws + WS_RIDX);
  int* gst = (int*)(ws + WS_GST);

  hipLaunchKernelGGL(k_prep, dim3(8 + NC * HH), dim3(256), 0, stream,
                     bseq, W1, alpha, ridx, gst, W1mbf);
  hipLaunchKernelGGL(k_fused, dim3(64 * 4), dim3(512), 0, stream,
                     q, k, bseq, W1mbf, ridx, gst, out);
}